// Round 1
// baseline (1535.987 us; speedup 1.0000x reference)
//
#include <hip/hip_runtime.h>
#include <hip/hip_bf16.h>
#include <math.h>

#define N_ROWS 8192
#define M_FACTS 8192
#define D_DIM 1024

typedef __bf16 bf16x8_t __attribute__((ext_vector_type(8)));
typedef __bf16 bf16x4_t __attribute__((ext_vector_type(4)));
typedef float f32x4_t __attribute__((ext_vector_type(4)));

#define BM 128
#define BN 128
#define BK 32
#define PADK 40  // bf16 elems per LDS row: 80B stride, 16B-aligned, 20-bank stride (<=2-way conflict = free)

// -------------------------------------------------------------------------
// Kernel 1: energy[n][m] = sum_d E[n][d] * F[m][d]  (fp32 via bf16x3 split)
// -------------------------------------------------------------------------
__global__ __launch_bounds__(256) void gemm1_energy(const float* __restrict__ A,
                                                    const float* __restrict__ B,
                                                    float* __restrict__ C) {
  __shared__ __align__(16) __bf16 sAh[BM * PADK];
  __shared__ __align__(16) __bf16 sAl[BM * PADK];
  __shared__ __align__(16) __bf16 sBh[BN * PADK];
  __shared__ __align__(16) __bf16 sBl[BN * PADK];

  const int tid = threadIdx.x;
  const int row0 = blockIdx.x * BM;  // n tile
  const int col0 = blockIdx.y * BN;  // m tile
  const int wave = tid >> 6;
  const int lane = tid & 63;
  const int wm = wave >> 1;  // 2x2 wave grid, each wave owns 64x64
  const int wn = wave & 1;
  const int lrow = lane & 15;
  const int quad = lane >> 4;

  f32x4_t acc[4][4];
#pragma unroll
  for (int i = 0; i < 4; i++)
#pragma unroll
    for (int j = 0; j < 4; j++) acc[i][j] = (f32x4_t){0.f, 0.f, 0.f, 0.f};

  for (int k0 = 0; k0 < D_DIM; k0 += BK) {
    __syncthreads();
    // Stage 128x32 fp32 tiles of A and B, split into bf16 hi/lo in LDS.
#pragma unroll
    for (int it = 0; it < 4; it++) {
      int flat = it * 256 + tid;      // 0..1023 float4 slots
      int r = flat >> 3;              // 8 float4 per row of 32 floats
      int kq = flat & 7;
      float4 va = *(const float4*)(A + (size_t)(row0 + r) * D_DIM + k0 + kq * 4);
      float4 vb = *(const float4*)(B + (size_t)(col0 + r) * D_DIM + k0 + kq * 4);
      float fa[4] = {va.x, va.y, va.z, va.w};
      float fb[4] = {vb.x, vb.y, vb.z, vb.w};
      bf16x4_t ah, al, bh, bl;
#pragma unroll
      for (int q = 0; q < 4; q++) {
        __bf16 h = (__bf16)fa[q];
        ah[q] = h;
        al[q] = (__bf16)(fa[q] - (float)h);
        __bf16 g = (__bf16)fb[q];
        bh[q] = g;
        bl[q] = (__bf16)(fb[q] - (float)g);
      }
      *(bf16x4_t*)(sAh + r * PADK + kq * 4) = ah;
      *(bf16x4_t*)(sAl + r * PADK + kq * 4) = al;
      *(bf16x4_t*)(sBh + r * PADK + kq * 4) = bh;
      *(bf16x4_t*)(sBl + r * PADK + kq * 4) = bl;
    }
    __syncthreads();

    bf16x8_t a_h[4], a_l[4], b_h[4], b_l[4];
#pragma unroll
    for (int i = 0; i < 4; i++) {
      int ra = wm * 64 + i * 16 + lrow;
      a_h[i] = *(const bf16x8_t*)(sAh + ra * PADK + quad * 8);
      a_l[i] = *(const bf16x8_t*)(sAl + ra * PADK + quad * 8);
      int rb = wn * 64 + i * 16 + lrow;
      b_h[i] = *(const bf16x8_t*)(sBh + rb * PADK + quad * 8);
      b_l[i] = *(const bf16x8_t*)(sBl + rb * PADK + quad * 8);
    }
#pragma unroll
    for (int i = 0; i < 4; i++)
#pragma unroll
      for (int j = 0; j < 4; j++) {
        acc[i][j] = __builtin_amdgcn_mfma_f32_16x16x32_bf16(a_h[i], b_h[j], acc[i][j], 0, 0, 0);
        acc[i][j] = __builtin_amdgcn_mfma_f32_16x16x32_bf16(a_h[i], b_l[j], acc[i][j], 0, 0, 0);
        acc[i][j] = __builtin_amdgcn_mfma_f32_16x16x32_bf16(a_l[i], b_h[j], acc[i][j], 0, 0, 0);
      }
  }

  // Epilogue: C/D layout col=lane&15, row=quad*4+reg
#pragma unroll
  for (int i = 0; i < 4; i++) {
    int rbase = row0 + wm * 64 + i * 16 + quad * 4;
#pragma unroll
    for (int j = 0; j < 4; j++) {
      int c = col0 + wn * 64 + j * 16 + lrow;
#pragma unroll
      for (int r = 0; r < 4; r++) {
        C[(size_t)(rbase + r) * M_FACTS + c] = acc[i][j][r];
      }
    }
  }
}

// -------------------------------------------------------------------------
// Kernel 2: in-place row softmax over M=8192, one block per row.
// Row lives in registers (32 fp32/thread) between passes.
// -------------------------------------------------------------------------
__global__ __launch_bounds__(256) void softmax_rows(float* __restrict__ W) {
  __shared__ float red[8];
  const int tid = threadIdx.x;
  float* p = W + (size_t)blockIdx.x * M_FACTS;

  float4 v[8];
  float mx = -3.4e38f;
#pragma unroll
  for (int i = 0; i < 8; i++) {
    v[i] = *(const float4*)(p + (size_t)(i * 256 + tid) * 4);
    mx = fmaxf(mx, fmaxf(fmaxf(v[i].x, v[i].y), fmaxf(v[i].z, v[i].w)));
  }
#pragma unroll
  for (int off = 32; off >= 1; off >>= 1) mx = fmaxf(mx, __shfl_xor(mx, off));
  const int wave = tid >> 6, lane = tid & 63;
  if (lane == 0) red[wave] = mx;
  __syncthreads();
  mx = fmaxf(fmaxf(red[0], red[1]), fmaxf(red[2], red[3]));

  float s = 0.f;
#pragma unroll
  for (int i = 0; i < 8; i++) {
    v[i].x = __expf(v[i].x - mx);
    v[i].y = __expf(v[i].y - mx);
    v[i].z = __expf(v[i].z - mx);
    v[i].w = __expf(v[i].w - mx);
    s += v[i].x + v[i].y + v[i].z + v[i].w;
  }
#pragma unroll
  for (int off = 32; off >= 1; off >>= 1) s += __shfl_xor(s, off);
  if (lane == 0) red[4 + wave] = s;
  __syncthreads();
  s = red[4] + red[5] + red[6] + red[7];
  float inv = 1.0f / s;
#pragma unroll
  for (int i = 0; i < 8; i++) {
    v[i].x *= inv;
    v[i].y *= inv;
    v[i].z *= inv;
    v[i].w *= inv;
    *(float4*)(p + (size_t)(i * 256 + tid) * 4) = v[i];
  }
}

// -------------------------------------------------------------------------
// Kernel 3: O[n][d] = sum_m W[n][m] * F[m][d]  (plain bf16 MFMA)
// F tile staged transposed into LDS (contraction index m is F's slow axis).
// -------------------------------------------------------------------------
__global__ __launch_bounds__(256) void gemm2_out(const float* __restrict__ W,
                                                 const float* __restrict__ F,
                                                 float* __restrict__ O) {
  __shared__ __align__(16) __bf16 sW[BM * PADK];
  __shared__ __align__(16) __bf16 sFt[BN * PADK];

  const int tid = threadIdx.x;
  const int row0 = blockIdx.x * BM;  // n tile
  const int col0 = blockIdx.y * BN;  // d tile
  const int wave = tid >> 6;
  const int lane = tid & 63;
  const int wm = wave >> 1;
  const int wn = wave & 1;
  const int lrow = lane & 15;
  const int quad = lane >> 4;

  f32x4_t acc[4][4];
#pragma unroll
  for (int i = 0; i < 4; i++)
#pragma unroll
    for (int j = 0; j < 4; j++) acc[i][j] = (f32x4_t){0.f, 0.f, 0.f, 0.f};

  for (int k0 = 0; k0 < M_FACTS; k0 += BK) {
    __syncthreads();
    // Stage W tile 128 rows x 32 m (k contiguous in global -> direct).
#pragma unroll
    for (int it = 0; it < 4; it++) {
      int flat = it * 256 + tid;
      int r = flat >> 3;
      int kq = flat & 7;
      float4 v = *(const float4*)(W + (size_t)(row0 + r) * M_FACTS + k0 + kq * 4);
      bf16x4_t h;
      h[0] = (__bf16)v.x;
      h[1] = (__bf16)v.y;
      h[2] = (__bf16)v.z;
      h[3] = (__bf16)v.w;
      *(bf16x4_t*)(sW + r * PADK + kq * 4) = h;
    }
    // Stage F tile 32 m-rows x 128 d-cols, transposed into LDS: sFt[d][m].
#pragma unroll
    for (int it = 0; it < 4; it++) {
      int flat = it * 256 + tid;
      int m = flat >> 5;   // 32 float4 per F row-chunk of 128 floats
      int dq = flat & 31;
      float4 v = *(const float4*)(F + (size_t)(k0 + m) * D_DIM + col0 + dq * 4);
      sFt[(dq * 4 + 0) * PADK + m] = (__bf16)v.x;
      sFt[(dq * 4 + 1) * PADK + m] = (__bf16)v.y;
      sFt[(dq * 4 + 2) * PADK + m] = (__bf16)v.z;
      sFt[(dq * 4 + 3) * PADK + m] = (__bf16)v.w;
    }
    __syncthreads();

    bf16x8_t a[4], b[4];
#pragma unroll
    for (int i = 0; i < 4; i++) {
      a[i] = *(const bf16x8_t*)(sW + (wm * 64 + i * 16 + lrow) * PADK + quad * 8);
      b[i] = *(const bf16x8_t*)(sFt + (wn * 64 + i * 16 + lrow) * PADK + quad * 8);
    }
#pragma unroll
    for (int i = 0; i < 4; i++)
#pragma unroll
      for (int j = 0; j < 4; j++)
        acc[i][j] = __builtin_amdgcn_mfma_f32_16x16x32_bf16(a[i], b[j], acc[i][j], 0, 0, 0);
  }

#pragma unroll
  for (int i = 0; i < 4; i++) {
    int rbase = row0 + wm * 64 + i * 16 + quad * 4;
#pragma unroll
    for (int j = 0; j < 4; j++) {
      int c = col0 + wn * 64 + j * 16 + lrow;
#pragma unroll
      for (int r = 0; r < 4; r++) {
        O[(size_t)(rbase + r) * D_DIM + c] = acc[i][j][r];
      }
    }
  }
}

extern "C" void kernel_launch(void* const* d_in, const int* in_sizes, int n_in,
                              void* d_out, int out_size, void* d_ws, size_t ws_size,
                              hipStream_t stream) {
  const float* E = (const float*)d_in[0];  // [N, D]
  const float* F = (const float*)d_in[1];  // [M, D]
  float* outputs = (float*)d_out;                              // [N, D]
  float* weights = (float*)d_out + (size_t)N_ROWS * D_DIM;     // [N, M]

  gemm1_energy<<<dim3(N_ROWS / BM, M_FACTS / BN), 256, 0, stream>>>(E, F, weights);
  softmax_rows<<<dim3(N_ROWS), 256, 0, stream>>>(weights);
  gemm2_out<<<dim3(N_ROWS / BM, D_DIM / BN), 256, 0, stream>>>(weights, F, outputs);
}

// Round 2
// 1022.803 us; speedup vs baseline: 1.5017x; 1.5017x over previous
//
#include <hip/hip_runtime.h>
#include <hip/hip_bf16.h>
#include <math.h>
#include <stdint.h>

#define N_ROWS 8192
#define M_FACTS 8192
#define D_DIM 1024

typedef __bf16 bf16x8_t __attribute__((ext_vector_type(8)));
typedef __bf16 bf16x4_t __attribute__((ext_vector_type(4)));
typedef float f32x4_t __attribute__((ext_vector_type(4)));

#define BM 128
#define BN 128
#define BK 32
#define PADK 40  // legacy padded stride for fallback kernels

// Async global->LDS, 16B per lane. LDS dest = wave-uniform base + lane*16.
__device__ __forceinline__ void gload_lds16(const void* g, void* lds) {
  __builtin_amdgcn_global_load_lds(
      (__attribute__((address_space(1))) void*)(uintptr_t)g,
      (__attribute__((address_space(3))) void*)(uint32_t)(uintptr_t)lds,
      16, 0, 0);
}

// =========================================================================
// Precompute kernels
// =========================================================================

// X fp32 [n] -> H,L bf16 hi/lo split. One float4 per thread, grid = n/1024.
__global__ __launch_bounds__(256) void split_hi_lo(const float* __restrict__ X,
                                                   __bf16* __restrict__ H,
                                                   __bf16* __restrict__ L) {
  int i = blockIdx.x * 256 + threadIdx.x;
  float4 v = ((const float4*)X)[i];
  float f[4] = {v.x, v.y, v.z, v.w};
  bf16x4_t h, l;
#pragma unroll
  for (int q = 0; q < 4; q++) {
    __bf16 hh = (__bf16)f[q];
    h[q] = hh;
    l[q] = (__bf16)(f[q] - (float)hh);
  }
  ((bf16x4_t*)H)[i] = h;
  ((bf16x4_t*)L)[i] = l;
}

// F fp32 [M][D] -> Ft bf16 [D][M]. 64x64 tiles via LDS.
__global__ __launch_bounds__(256) void transpose_f_bf16(const float* __restrict__ F,
                                                        __bf16* __restrict__ Ft) {
  __shared__ __bf16 t[64 * 68];
  const int tid = threadIdx.x;
  const int m0 = blockIdx.x * 64, d0 = blockIdx.y * 64;
#pragma unroll
  for (int p = 0; p < 4; p++) {
    int flat = p * 256 + tid;
    int m = flat >> 4, dq = flat & 15;
    float4 v = *(const float4*)(F + (size_t)(m0 + m) * D_DIM + d0 + dq * 4);
    bf16x4_t h;
    h[0] = (__bf16)v.x;
    h[1] = (__bf16)v.y;
    h[2] = (__bf16)v.z;
    h[3] = (__bf16)v.w;
    *(bf16x4_t*)(t + m * 68 + dq * 4) = h;
  }
  __syncthreads();
  // lanes read consecutive d (conflict-free), write 16B chunks per m-run
  int d = tid & 63, mc = (tid >> 6) * 16;
  bf16x8_t o0, o1;
#pragma unroll
  for (int j = 0; j < 8; j++) o0[j] = t[(mc + j) * 68 + d];
#pragma unroll
  for (int j = 0; j < 8; j++) o1[j] = t[(mc + 8 + j) * 68 + d];
  __bf16* dst = Ft + (size_t)(d0 + d) * M_FACTS + m0 + mc;
  *(bf16x8_t*)(dst) = o0;
  *(bf16x8_t*)(dst + 8) = o1;
}

// =========================================================================
// GEMM1 fast: energy = Eh*Fh^T + Eh*Fl^T + El*Fh^T, m97-style async staging
// =========================================================================
__global__ __launch_bounds__(256) void gemm1_fast(const __bf16* __restrict__ Eh,
                                                  const __bf16* __restrict__ El,
                                                  const __bf16* __restrict__ Fh,
                                                  const __bf16* __restrict__ Fl,
                                                  float* __restrict__ C) {
  __shared__ __bf16 sAh[BM * BK], sAl[BM * BK], sBh[BN * BK], sBl[BN * BK];
  const int tid = threadIdx.x;
  const int wave = tid >> 6, lane = tid & 63;
  const int row0 = blockIdx.x * BM, col0 = blockIdx.y * BN;
  const int wm = wave >> 1, wn = wave & 1;
  const int lrow = lane & 15, quad = lane >> 4;

  f32x4_t acc[4][4];
#pragma unroll
  for (int i = 0; i < 4; i++)
#pragma unroll
    for (int j = 0; j < 4; j++) acc[i][j] = (f32x4_t){0.f, 0.f, 0.f, 0.f};

  for (int k0 = 0; k0 < D_DIM; k0 += BK) {
#pragma unroll
    for (int r = 0; r < 2; r++) {
      int c = (r * 4 + wave) * 64 + lane;  // 16B chunk id, 0..511
      int row = c >> 2;
      int ko = (c & 3) << 3;
      size_t ga = (size_t)(row0 + row) * D_DIM + k0 + ko;
      size_t gb = (size_t)(col0 + row) * D_DIM + k0 + ko;
      gload_lds16(Eh + ga, sAh + c * 8);
      gload_lds16(El + ga, sAl + c * 8);
      gload_lds16(Fh + gb, sBh + c * 8);
      gload_lds16(Fl + gb, sBl + c * 8);
    }
    __syncthreads();

    bf16x8_t ah[4], al[4], bh[4], bl[4];
#pragma unroll
    for (int i = 0; i < 4; i++) {
      int ra = (wm * 64 + i * 16 + lrow) * BK + quad * 8;
      ah[i] = *(const bf16x8_t*)(sAh + ra);
      al[i] = *(const bf16x8_t*)(sAl + ra);
      int rb = (wn * 64 + i * 16 + lrow) * BK + quad * 8;
      bh[i] = *(const bf16x8_t*)(sBh + rb);
      bl[i] = *(const bf16x8_t*)(sBl + rb);
    }
#pragma unroll
    for (int i = 0; i < 4; i++)
#pragma unroll
      for (int j = 0; j < 4; j++) {
        acc[i][j] = __builtin_amdgcn_mfma_f32_16x16x32_bf16(ah[i], bh[j], acc[i][j], 0, 0, 0);
        acc[i][j] = __builtin_amdgcn_mfma_f32_16x16x32_bf16(ah[i], bl[j], acc[i][j], 0, 0, 0);
        acc[i][j] = __builtin_amdgcn_mfma_f32_16x16x32_bf16(al[i], bh[j], acc[i][j], 0, 0, 0);
      }
    __syncthreads();
  }

#pragma unroll
  for (int i = 0; i < 4; i++) {
    int rbase = row0 + wm * 64 + i * 16 + quad * 4;
#pragma unroll
    for (int j = 0; j < 4; j++) {
      int c = col0 + wn * 64 + j * 16 + lrow;
#pragma unroll
      for (int r = 0; r < 4; r++) C[(size_t)(rbase + r) * M_FACTS + c] = acc[i][j][r];
    }
  }
}

// =========================================================================
// GEMM2 fast: O = Wb @ Ft^T-layout (both bf16, contraction m contiguous)
// =========================================================================
__global__ __launch_bounds__(256) void gemm2_fast(const __bf16* __restrict__ Wb,
                                                  const __bf16* __restrict__ Ft,
                                                  float* __restrict__ O) {
  __shared__ __bf16 sW[BM * BK], sF[BN * BK];
  const int tid = threadIdx.x;
  const int wave = tid >> 6, lane = tid & 63;
  const int row0 = blockIdx.x * BM, col0 = blockIdx.y * BN;
  const int wm = wave >> 1, wn = wave & 1;
  const int lrow = lane & 15, quad = lane >> 4;

  f32x4_t acc[4][4];
#pragma unroll
  for (int i = 0; i < 4; i++)
#pragma unroll
    for (int j = 0; j < 4; j++) acc[i][j] = (f32x4_t){0.f, 0.f, 0.f, 0.f};

  for (int k0 = 0; k0 < M_FACTS; k0 += BK) {
#pragma unroll
    for (int r = 0; r < 2; r++) {
      int c = (r * 4 + wave) * 64 + lane;
      int row = c >> 2;
      int ko = (c & 3) << 3;
      gload_lds16(Wb + (size_t)(row0 + row) * M_FACTS + k0 + ko, sW + c * 8);
      gload_lds16(Ft + (size_t)(col0 + row) * M_FACTS + k0 + ko, sF + c * 8);
    }
    __syncthreads();

    bf16x8_t a[4], b[4];
#pragma unroll
    for (int i = 0; i < 4; i++) {
      a[i] = *(const bf16x8_t*)(sW + (wm * 64 + i * 16 + lrow) * BK + quad * 8);
      b[i] = *(const bf16x8_t*)(sF + (wn * 64 + i * 16 + lrow) * BK + quad * 8);
    }
#pragma unroll
    for (int i = 0; i < 4; i++)
#pragma unroll
      for (int j = 0; j < 4; j++)
        acc[i][j] = __builtin_amdgcn_mfma_f32_16x16x32_bf16(a[i], b[j], acc[i][j], 0, 0, 0);
    __syncthreads();
  }

#pragma unroll
  for (int i = 0; i < 4; i++) {
    int rbase = row0 + wm * 64 + i * 16 + quad * 4;
#pragma unroll
    for (int j = 0; j < 4; j++) {
      int c = col0 + wn * 64 + j * 16 + lrow;
#pragma unroll
      for (int r = 0; r < 4; r++) O[(size_t)(rbase + r) * D_DIM + c] = acc[i][j][r];
    }
  }
}

// GEMM2 mid: A = W fp32 (convert in staging), B = Ft via async. Tier-B path.
__global__ __launch_bounds__(256) void gemm2_mid(const float* __restrict__ W,
                                                 const __bf16* __restrict__ Ft,
                                                 float* __restrict__ O) {
  __shared__ __bf16 sW[BM * BK], sF[BN * BK];
  const int tid = threadIdx.x;
  const int wave = tid >> 6, lane = tid & 63;
  const int row0 = blockIdx.x * BM, col0 = blockIdx.y * BN;
  const int wm = wave >> 1, wn = wave & 1;
  const int lrow = lane & 15, quad = lane >> 4;

  f32x4_t acc[4][4];
#pragma unroll
  for (int i = 0; i < 4; i++)
#pragma unroll
    for (int j = 0; j < 4; j++) acc[i][j] = (f32x4_t){0.f, 0.f, 0.f, 0.f};

  for (int k0 = 0; k0 < M_FACTS; k0 += BK) {
#pragma unroll
    for (int r = 0; r < 2; r++) {
      int c = (r * 4 + wave) * 64 + lane;
      int row = c >> 2;
      int ko = (c & 3) << 3;
      gload_lds16(Ft + (size_t)(col0 + row) * M_FACTS + k0 + ko, sF + c * 8);
    }
#pragma unroll
    for (int it = 0; it < 4; it++) {
      int flat = it * 256 + tid;
      int r = flat >> 3, q = flat & 7;
      float4 v = *(const float4*)(W + (size_t)(row0 + r) * M_FACTS + k0 + q * 4);
      bf16x4_t h;
      h[0] = (__bf16)v.x;
      h[1] = (__bf16)v.y;
      h[2] = (__bf16)v.z;
      h[3] = (__bf16)v.w;
      *(bf16x4_t*)(sW + r * BK + q * 4) = h;
    }
    __syncthreads();

    bf16x8_t a[4], b[4];
#pragma unroll
    for (int i = 0; i < 4; i++) {
      a[i] = *(const bf16x8_t*)(sW + (wm * 64 + i * 16 + lrow) * BK + quad * 8);
      b[i] = *(const bf16x8_t*)(sF + (wn * 64 + i * 16 + lrow) * BK + quad * 8);
    }
#pragma unroll
    for (int i = 0; i < 4; i++)
#pragma unroll
      for (int j = 0; j < 4; j++)
        acc[i][j] = __builtin_amdgcn_mfma_f32_16x16x32_bf16(a[i], b[j], acc[i][j], 0, 0, 0);
    __syncthreads();
  }

#pragma unroll
  for (int i = 0; i < 4; i++) {
    int rbase = row0 + wm * 64 + i * 16 + quad * 4;
#pragma unroll
    for (int j = 0; j < 4; j++) {
      int c = col0 + wn * 64 + j * 16 + lrow;
#pragma unroll
      for (int r = 0; r < 4; r++) O[(size_t)(rbase + r) * D_DIM + c] = acc[i][j][r];
    }
  }
}

// =========================================================================
// Softmax (optionally emitting bf16 copy of weights)
// =========================================================================
template <bool EMIT_BF16>
__global__ __launch_bounds__(256) void softmax_rows_t(float* __restrict__ W,
                                                      __bf16* __restrict__ Wb) {
  __shared__ float red[8];
  const int tid = threadIdx.x;
  float* p = W + (size_t)blockIdx.x * M_FACTS;

  float4 v[8];
  float mx = -3.4e38f;
#pragma unroll
  for (int i = 0; i < 8; i++) {
    v[i] = *(const float4*)(p + (size_t)(i * 256 + tid) * 4);
    mx = fmaxf(mx, fmaxf(fmaxf(v[i].x, v[i].y), fmaxf(v[i].z, v[i].w)));
  }
#pragma unroll
  for (int off = 32; off >= 1; off >>= 1) mx = fmaxf(mx, __shfl_xor(mx, off));
  const int wave = tid >> 6, lane = tid & 63;
  if (lane == 0) red[wave] = mx;
  __syncthreads();
  mx = fmaxf(fmaxf(red[0], red[1]), fmaxf(red[2], red[3]));

  float s = 0.f;
#pragma unroll
  for (int i = 0; i < 8; i++) {
    v[i].x = __expf(v[i].x - mx);
    v[i].y = __expf(v[i].y - mx);
    v[i].z = __expf(v[i].z - mx);
    v[i].w = __expf(v[i].w - mx);
    s += v[i].x + v[i].y + v[i].z + v[i].w;
  }
#pragma unroll
  for (int off = 32; off >= 1; off >>= 1) s += __shfl_xor(s, off);
  if (lane == 0) red[4 + wave] = s;
  __syncthreads();
  s = red[4] + red[5] + red[6] + red[7];
  float inv = 1.0f / s;
  __bf16* pb = EMIT_BF16 ? (Wb + (size_t)blockIdx.x * M_FACTS) : nullptr;
#pragma unroll
  for (int i = 0; i < 8; i++) {
    v[i].x *= inv;
    v[i].y *= inv;
    v[i].z *= inv;
    v[i].w *= inv;
    *(float4*)(p + (size_t)(i * 256 + tid) * 4) = v[i];
    if (EMIT_BF16) {
      bf16x4_t h;
      h[0] = (__bf16)v[i].x;
      h[1] = (__bf16)v[i].y;
      h[2] = (__bf16)v[i].z;
      h[3] = (__bf16)v[i].w;
      *(bf16x4_t*)(pb + (size_t)(i * 256 + tid) * 4) = h;
    }
  }
}

// =========================================================================
// Fallback (round-1) kernels
// =========================================================================
__global__ __launch_bounds__(256) void gemm1_energy(const float* __restrict__ A,
                                                    const float* __restrict__ B,
                                                    float* __restrict__ C) {
  __shared__ __align__(16) __bf16 sAh[BM * PADK];
  __shared__ __align__(16) __bf16 sAl[BM * PADK];
  __shared__ __align__(16) __bf16 sBh[BN * PADK];
  __shared__ __align__(16) __bf16 sBl[BN * PADK];

  const int tid = threadIdx.x;
  const int row0 = blockIdx.x * BM, col0 = blockIdx.y * BN;
  const int wave = tid >> 6, lane = tid & 63;
  const int wm = wave >> 1, wn = wave & 1;
  const int lrow = lane & 15, quad = lane >> 4;

  f32x4_t acc[4][4];
#pragma unroll
  for (int i = 0; i < 4; i++)
#pragma unroll
    for (int j = 0; j < 4; j++) acc[i][j] = (f32x4_t){0.f, 0.f, 0.f, 0.f};

  for (int k0 = 0; k0 < D_DIM; k0 += BK) {
    __syncthreads();
#pragma unroll
    for (int it = 0; it < 4; it++) {
      int flat = it * 256 + tid;
      int r = flat >> 3, kq = flat & 7;
      float4 va = *(const float4*)(A + (size_t)(row0 + r) * D_DIM + k0 + kq * 4);
      float4 vb = *(const float4*)(B + (size_t)(col0 + r) * D_DIM + k0 + kq * 4);
      float fa[4] = {va.x, va.y, va.z, va.w};
      float fb[4] = {vb.x, vb.y, vb.z, vb.w};
      bf16x4_t ah, al, bh, bl;
#pragma unroll
      for (int q = 0; q < 4; q++) {
        __bf16 h = (__bf16)fa[q];
        ah[q] = h;
        al[q] = (__bf16)(fa[q] - (float)h);
        __bf16 g = (__bf16)fb[q];
        bh[q] = g;
        bl[q] = (__bf16)(fb[q] - (float)g);
      }
      *(bf16x4_t*)(sAh + r * PADK + kq * 4) = ah;
      *(bf16x4_t*)(sAl + r * PADK + kq * 4) = al;
      *(bf16x4_t*)(sBh + r * PADK + kq * 4) = bh;
      *(bf16x4_t*)(sBl + r * PADK + kq * 4) = bl;
    }
    __syncthreads();

    bf16x8_t a_h[4], a_l[4], b_h[4], b_l[4];
#pragma unroll
    for (int i = 0; i < 4; i++) {
      int ra = wm * 64 + i * 16 + lrow;
      a_h[i] = *(const bf16x8_t*)(sAh + ra * PADK + quad * 8);
      a_l[i] = *(const bf16x8_t*)(sAl + ra * PADK + quad * 8);
      int rb = wn * 64 + i * 16 + lrow;
      b_h[i] = *(const bf16x8_t*)(sBh + rb * PADK + quad * 8);
      b_l[i] = *(const bf16x8_t*)(sBl + rb * PADK + quad * 8);
    }
#pragma unroll
    for (int i = 0; i < 4; i++)
#pragma unroll
      for (int j = 0; j < 4; j++) {
        acc[i][j] = __builtin_amdgcn_mfma_f32_16x16x32_bf16(a_h[i], b_h[j], acc[i][j], 0, 0, 0);
        acc[i][j] = __builtin_amdgcn_mfma_f32_16x16x32_bf16(a_h[i], b_l[j], acc[i][j], 0, 0, 0);
        acc[i][j] = __builtin_amdgcn_mfma_f32_16x16x32_bf16(a_l[i], b_h[j], acc[i][j], 0, 0, 0);
      }
  }

#pragma unroll
  for (int i = 0; i < 4; i++) {
    int rbase = row0 + wm * 64 + i * 16 + quad * 4;
#pragma unroll
    for (int j = 0; j < 4; j++) {
      int c = col0 + wn * 64 + j * 16 + lrow;
#pragma unroll
      for (int r = 0; r < 4; r++) C[(size_t)(rbase + r) * M_FACTS + c] = acc[i][j][r];
    }
  }
}

__global__ __launch_bounds__(256) void gemm2_out(const float* __restrict__ W,
                                                 const float* __restrict__ F,
                                                 float* __restrict__ O) {
  __shared__ __align__(16) __bf16 sW[BM * PADK];
  __shared__ __align__(16) __bf16 sFt[BN * PADK];

  const int tid = threadIdx.x;
  const int row0 = blockIdx.x * BM, col0 = blockIdx.y * BN;
  const int wave = tid >> 6, lane = tid & 63;
  const int wm = wave >> 1, wn = wave & 1;
  const int lrow = lane & 15, quad = lane >> 4;

  f32x4_t acc[4][4];
#pragma unroll
  for (int i = 0; i < 4; i++)
#pragma unroll
    for (int j = 0; j < 4; j++) acc[i][j] = (f32x4_t){0.f, 0.f, 0.f, 0.f};

  for (int k0 = 0; k0 < M_FACTS; k0 += BK) {
    __syncthreads();
#pragma unroll
    for (int it = 0; it < 4; it++) {
      int flat = it * 256 + tid;
      int r = flat >> 3, kq = flat & 7;
      float4 v = *(const float4*)(W + (size_t)(row0 + r) * M_FACTS + k0 + kq * 4);
      bf16x4_t h;
      h[0] = (__bf16)v.x;
      h[1] = (__bf16)v.y;
      h[2] = (__bf16)v.z;
      h[3] = (__bf16)v.w;
      *(bf16x4_t*)(sW + r * PADK + kq * 4) = h;
    }
#pragma unroll
    for (int it = 0; it < 4; it++) {
      int flat = it * 256 + tid;
      int m = flat >> 5, dq = flat & 31;
      float4 v = *(const float4*)(F + (size_t)(k0 + m) * D_DIM + col0 + dq * 4);
      sFt[(dq * 4 + 0) * PADK + m] = (__bf16)v.x;
      sFt[(dq * 4 + 1) * PADK + m] = (__bf16)v.y;
      sFt[(dq * 4 + 2) * PADK + m] = (__bf16)v.z;
      sFt[(dq * 4 + 3) * PADK + m] = (__bf16)v.w;
    }
    __syncthreads();

    bf16x8_t a[4], b[4];
#pragma unroll
    for (int i = 0; i < 4; i++) {
      a[i] = *(const bf16x8_t*)(sW + (wm * 64 + i * 16 + lrow) * PADK + quad * 8);
      b[i] = *(const bf16x8_t*)(sFt + (wn * 64 + i * 16 + lrow) * PADK + quad * 8);
    }
#pragma unroll
    for (int i = 0; i < 4; i++)
#pragma unroll
      for (int j = 0; j < 4; j++)
        acc[i][j] = __builtin_amdgcn_mfma_f32_16x16x32_bf16(a[i], b[j], acc[i][j], 0, 0, 0);
  }

#pragma unroll
  for (int i = 0; i < 4; i++) {
    int rbase = row0 + wm * 64 + i * 16 + quad * 4;
#pragma unroll
    for (int j = 0; j < 4; j++) {
      int c = col0 + wn * 64 + j * 16 + lrow;
#pragma unroll
      for (int r = 0; r < 4; r++) O[(size_t)(rbase + r) * D_DIM + c] = acc[i][j][r];
    }
  }
}

// =========================================================================
extern "C" void kernel_launch(void* const* d_in, const int* in_sizes, int n_in,
                              void* d_out, int out_size, void* d_ws, size_t ws_size,
                              hipStream_t stream) {
  const float* E = (const float*)d_in[0];  // [N, D]
  const float* F = (const float*)d_in[1];  // [M, D]
  float* outputs = (float*)d_out;                           // [N, D]
  float* weights = (float*)d_out + (size_t)N_ROWS * D_DIM;  // [N, M]

  const size_t MB = 1ull << 20;
  char* ws = (char*)d_ws;
  __bf16* Ft = (__bf16*)(ws);            // 16 MB  [D][M]
  __bf16* Eh = (__bf16*)(ws + 16 * MB);  // 16 MB
  __bf16* El = (__bf16*)(ws + 32 * MB);  // 16 MB
  __bf16* Fh = (__bf16*)(ws + 48 * MB);  // 16 MB
  __bf16* Fl = (__bf16*)(ws + 64 * MB);  // 16 MB
  __bf16* Wb = (__bf16*)(ws + 80 * MB);  // 128 MB [N][M]

  const bool hasWb = ws_size >= 208 * MB;
  const bool hasSplit = ws_size >= 80 * MB;
  const bool hasFt = ws_size >= 16 * MB;

  if (hasFt) {
    transpose_f_bf16<<<dim3(M_FACTS / 64, D_DIM / 64), 256, 0, stream>>>(F, Ft);
  }
  if (hasSplit) {
    split_hi_lo<<<dim3((N_ROWS * D_DIM) / 1024), 256, 0, stream>>>(E, Eh, El);
    split_hi_lo<<<dim3((M_FACTS * D_DIM) / 1024), 256, 0, stream>>>(F, Fh, Fl);
    gemm1_fast<<<dim3(N_ROWS / BM, M_FACTS / BN), 256, 0, stream>>>(Eh, El, Fh, Fl, weights);
  } else {
    gemm1_energy<<<dim3(N_ROWS / BM, M_FACTS / BN), 256, 0, stream>>>(E, F, weights);
  }

  if (hasWb) {
    softmax_rows_t<true><<<dim3(N_ROWS), 256, 0, stream>>>(weights, Wb);
  } else {
    softmax_rows_t<false><<<dim3(N_ROWS), 256, 0, stream>>>(weights, nullptr);
  }

  if (hasWb) {
    gemm2_fast<<<dim3(N_ROWS / BM, D_DIM / BN), 256, 0, stream>>>(Wb, Ft, outputs);
  } else if (hasFt) {
    gemm2_mid<<<dim3(N_ROWS / BM, D_DIM / BN), 256, 0, stream>>>(weights, Ft, outputs);
  } else {
    gemm2_out<<<dim3(N_ROWS / BM, D_DIM / BN), 256, 0, stream>>>(weights, F, outputs);
  }
}

// Round 3
// 1011.563 us; speedup vs baseline: 1.5184x; 1.0111x over previous
//
#include <hip/hip_runtime.h>
#include <hip/hip_bf16.h>
#include <math.h>
#include <stdint.h>

#define N_ROWS 8192
#define M_FACTS 8192
#define D_DIM 1024

typedef __bf16 bf16x8_t __attribute__((ext_vector_type(8)));
typedef __bf16 bf16x4_t __attribute__((ext_vector_type(4)));
typedef float f32x4_t __attribute__((ext_vector_type(4)));

#define BM 128
#define BN 128
#define BK 32
#define PADK 40  // legacy padded stride for fallback kernels

// Async global->LDS, 16B per lane. LDS dest = wave-uniform base + lane*16.
__device__ __forceinline__ void gload_lds16(const void* g, void* lds) {
  __builtin_amdgcn_global_load_lds(
      (__attribute__((address_space(1))) void*)(uintptr_t)g,
      (__attribute__((address_space(3))) void*)(uint32_t)(uintptr_t)lds,
      16, 0, 0);
}

// =========================================================================
// Precompute kernels
// =========================================================================

__global__ __launch_bounds__(256) void split_hi_lo(const float* __restrict__ X,
                                                   __bf16* __restrict__ H,
                                                   __bf16* __restrict__ L) {
  int i = blockIdx.x * 256 + threadIdx.x;
  float4 v = ((const float4*)X)[i];
  float f[4] = {v.x, v.y, v.z, v.w};
  bf16x4_t h, l;
#pragma unroll
  for (int q = 0; q < 4; q++) {
    __bf16 hh = (__bf16)f[q];
    h[q] = hh;
    l[q] = (__bf16)(f[q] - (float)hh);
  }
  ((bf16x4_t*)H)[i] = h;
  ((bf16x4_t*)L)[i] = l;
}

// F fp32 [M][D] -> Ft bf16 [D][M]. 64x64 tiles via LDS.
__global__ __launch_bounds__(256) void transpose_f_bf16(const float* __restrict__ F,
                                                        __bf16* __restrict__ Ft) {
  __shared__ __bf16 t[64 * 68];
  const int tid = threadIdx.x;
  const int m0 = blockIdx.x * 64, d0 = blockIdx.y * 64;
#pragma unroll
  for (int p = 0; p < 4; p++) {
    int flat = p * 256 + tid;
    int m = flat >> 4, dq = flat & 15;
    float4 v = *(const float4*)(F + (size_t)(m0 + m) * D_DIM + d0 + dq * 4);
    bf16x4_t h;
    h[0] = (__bf16)v.x;
    h[1] = (__bf16)v.y;
    h[2] = (__bf16)v.z;
    h[3] = (__bf16)v.w;
    *(bf16x4_t*)(t + m * 68 + dq * 4) = h;
  }
  __syncthreads();
  int d = tid & 63, mc = (tid >> 6) * 16;
  bf16x8_t o0, o1;
#pragma unroll
  for (int j = 0; j < 8; j++) o0[j] = t[(mc + j) * 68 + d];
#pragma unroll
  for (int j = 0; j < 8; j++) o1[j] = t[(mc + 8 + j) * 68 + d];
  __bf16* dst = Ft + (size_t)(d0 + d) * M_FACTS + m0 + mc;
  *(bf16x8_t*)(dst) = o0;
  *(bf16x8_t*)(dst + 8) = o1;
}

// =========================================================================
// GEMM1 fast: energy = Eh*Fh^T + Eh*Fl^T + El*Fh^T, m97-style async staging
// =========================================================================
__global__ __launch_bounds__(256) void gemm1_fast(const __bf16* __restrict__ Eh,
                                                  const __bf16* __restrict__ El,
                                                  const __bf16* __restrict__ Fh,
                                                  const __bf16* __restrict__ Fl,
                                                  float* __restrict__ C) {
  __shared__ __bf16 sAh[BM * BK], sAl[BM * BK], sBh[BN * BK], sBl[BN * BK];
  const int tid = threadIdx.x;
  const int wave = tid >> 6, lane = tid & 63;
  const int row0 = blockIdx.x * BM, col0 = blockIdx.y * BN;
  const int wm = wave >> 1, wn = wave & 1;
  const int lrow = lane & 15, quad = lane >> 4;

  f32x4_t acc[4][4];
#pragma unroll
  for (int i = 0; i < 4; i++)
#pragma unroll
    for (int j = 0; j < 4; j++) acc[i][j] = (f32x4_t){0.f, 0.f, 0.f, 0.f};

  for (int k0 = 0; k0 < D_DIM; k0 += BK) {
#pragma unroll
    for (int r = 0; r < 2; r++) {
      int c = (r * 4 + wave) * 64 + lane;  // 16B chunk id, 0..511
      int row = c >> 2;
      int ko = (c & 3) << 3;
      size_t ga = (size_t)(row0 + row) * D_DIM + k0 + ko;
      size_t gb = (size_t)(col0 + row) * D_DIM + k0 + ko;
      gload_lds16(Eh + ga, sAh + c * 8);
      gload_lds16(El + ga, sAl + c * 8);
      gload_lds16(Fh + gb, sBh + c * 8);
      gload_lds16(Fl + gb, sBl + c * 8);
    }
    __syncthreads();

    bf16x8_t ah[4], al[4], bh[4], bl[4];
#pragma unroll
    for (int i = 0; i < 4; i++) {
      int ra = (wm * 64 + i * 16 + lrow) * BK + quad * 8;
      ah[i] = *(const bf16x8_t*)(sAh + ra);
      al[i] = *(const bf16x8_t*)(sAl + ra);
      int rb = (wn * 64 + i * 16 + lrow) * BK + quad * 8;
      bh[i] = *(const bf16x8_t*)(sBh + rb);
      bl[i] = *(const bf16x8_t*)(sBl + rb);
    }
#pragma unroll
    for (int i = 0; i < 4; i++)
#pragma unroll
      for (int j = 0; j < 4; j++) {
        acc[i][j] = __builtin_amdgcn_mfma_f32_16x16x32_bf16(ah[i], bh[j], acc[i][j], 0, 0, 0);
        acc[i][j] = __builtin_amdgcn_mfma_f32_16x16x32_bf16(ah[i], bl[j], acc[i][j], 0, 0, 0);
        acc[i][j] = __builtin_amdgcn_mfma_f32_16x16x32_bf16(al[i], bh[j], acc[i][j], 0, 0, 0);
      }
    __syncthreads();
  }

#pragma unroll
  for (int i = 0; i < 4; i++) {
    int rbase = row0 + wm * 64 + i * 16 + quad * 4;
#pragma unroll
    for (int j = 0; j < 4; j++) {
      int c = col0 + wn * 64 + j * 16 + lrow;
#pragma unroll
      for (int r = 0; r < 4; r++) C[(size_t)(rbase + r) * M_FACTS + c] = acc[i][j][r];
    }
  }
}

// =========================================================================
// GEMM2 fast: O[out_row0 + n][d] = sum_m Wb[n][m] * Ft[d][m]
// Wb is chunk-local (rows 0..nrows-1 of the current chunk).
// =========================================================================
__global__ __launch_bounds__(256) void gemm2_fast(const __bf16* __restrict__ Wb,
                                                  const __bf16* __restrict__ Ft,
                                                  float* __restrict__ O,
                                                  int out_row0) {
  __shared__ __bf16 sW[BM * BK], sF[BN * BK];
  const int tid = threadIdx.x;
  const int wave = tid >> 6, lane = tid & 63;
  const int row0 = blockIdx.x * BM, col0 = blockIdx.y * BN;
  const int wm = wave >> 1, wn = wave & 1;
  const int lrow = lane & 15, quad = lane >> 4;

  f32x4_t acc[4][4];
#pragma unroll
  for (int i = 0; i < 4; i++)
#pragma unroll
    for (int j = 0; j < 4; j++) acc[i][j] = (f32x4_t){0.f, 0.f, 0.f, 0.f};

  for (int k0 = 0; k0 < M_FACTS; k0 += BK) {
#pragma unroll
    for (int r = 0; r < 2; r++) {
      int c = (r * 4 + wave) * 64 + lane;
      int row = c >> 2;
      int ko = (c & 3) << 3;
      gload_lds16(Wb + (size_t)(row0 + row) * M_FACTS + k0 + ko, sW + c * 8);
      gload_lds16(Ft + (size_t)(col0 + row) * M_FACTS + k0 + ko, sF + c * 8);
    }
    __syncthreads();

    bf16x8_t a[4], b[4];
#pragma unroll
    for (int i = 0; i < 4; i++) {
      a[i] = *(const bf16x8_t*)(sW + (wm * 64 + i * 16 + lrow) * BK + quad * 8);
      b[i] = *(const bf16x8_t*)(sF + (wn * 64 + i * 16 + lrow) * BK + quad * 8);
    }
#pragma unroll
    for (int i = 0; i < 4; i++)
#pragma unroll
      for (int j = 0; j < 4; j++)
        acc[i][j] = __builtin_amdgcn_mfma_f32_16x16x32_bf16(a[i], b[j], acc[i][j], 0, 0, 0);
    __syncthreads();
  }

#pragma unroll
  for (int i = 0; i < 4; i++) {
    int rbase = out_row0 + row0 + wm * 64 + i * 16 + quad * 4;
#pragma unroll
    for (int j = 0; j < 4; j++) {
      int c = col0 + wn * 64 + j * 16 + lrow;
#pragma unroll
      for (int r = 0; r < 4; r++) O[(size_t)(rbase + r) * D_DIM + c] = acc[i][j][r];
    }
  }
}

// GEMM2 mid: A = W fp32 (convert in staging), B = Ft via async. Low tier.
__global__ __launch_bounds__(256) void gemm2_mid(const float* __restrict__ W,
                                                 const __bf16* __restrict__ Ft,
                                                 float* __restrict__ O) {
  __shared__ __bf16 sW[BM * BK], sF[BN * BK];
  const int tid = threadIdx.x;
  const int wave = tid >> 6, lane = tid & 63;
  const int row0 = blockIdx.x * BM, col0 = blockIdx.y * BN;
  const int wm = wave >> 1, wn = wave & 1;
  const int lrow = lane & 15, quad = lane >> 4;

  f32x4_t acc[4][4];
#pragma unroll
  for (int i = 0; i < 4; i++)
#pragma unroll
    for (int j = 0; j < 4; j++) acc[i][j] = (f32x4_t){0.f, 0.f, 0.f, 0.f};

  for (int k0 = 0; k0 < M_FACTS; k0 += BK) {
#pragma unroll
    for (int r = 0; r < 2; r++) {
      int c = (r * 4 + wave) * 64 + lane;
      int row = c >> 2;
      int ko = (c & 3) << 3;
      gload_lds16(Ft + (size_t)(col0 + row) * M_FACTS + k0 + ko, sF + c * 8);
    }
#pragma unroll
    for (int it = 0; it < 4; it++) {
      int flat = it * 256 + tid;
      int r = flat >> 3, q = flat & 7;
      float4 v = *(const float4*)(W + (size_t)(row0 + r) * M_FACTS + k0 + q * 4);
      bf16x4_t h;
      h[0] = (__bf16)v.x;
      h[1] = (__bf16)v.y;
      h[2] = (__bf16)v.z;
      h[3] = (__bf16)v.w;
      *(bf16x4_t*)(sW + r * BK + q * 4) = h;
    }
    __syncthreads();

    bf16x8_t a[4], b[4];
#pragma unroll
    for (int i = 0; i < 4; i++) {
      a[i] = *(const bf16x8_t*)(sW + (wm * 64 + i * 16 + lrow) * BK + quad * 8);
      b[i] = *(const bf16x8_t*)(sF + (wn * 64 + i * 16 + lrow) * BK + quad * 8);
    }
#pragma unroll
    for (int i = 0; i < 4; i++)
#pragma unroll
      for (int j = 0; j < 4; j++)
        acc[i][j] = __builtin_amdgcn_mfma_f32_16x16x32_bf16(a[i], b[j], acc[i][j], 0, 0, 0);
    __syncthreads();
  }

#pragma unroll
  for (int i = 0; i < 4; i++) {
    int rbase = row0 + wm * 64 + i * 16 + quad * 4;
#pragma unroll
    for (int j = 0; j < 4; j++) {
      int c = col0 + wn * 64 + j * 16 + lrow;
#pragma unroll
      for (int r = 0; r < 4; r++) O[(size_t)(rbase + r) * D_DIM + c] = acc[i][j][r];
    }
  }
}

// =========================================================================
// Softmax (optionally emitting bf16 copy of weights). Pointers may be
// pre-offset by the caller for chunked processing.
// =========================================================================
template <bool EMIT_BF16>
__global__ __launch_bounds__(256) void softmax_rows_t(float* __restrict__ W,
                                                      __bf16* __restrict__ Wb) {
  __shared__ float red[8];
  const int tid = threadIdx.x;
  float* p = W + (size_t)blockIdx.x * M_FACTS;

  float4 v[8];
  float mx = -3.4e38f;
#pragma unroll
  for (int i = 0; i < 8; i++) {
    v[i] = *(const float4*)(p + (size_t)(i * 256 + tid) * 4);
    mx = fmaxf(mx, fmaxf(fmaxf(v[i].x, v[i].y), fmaxf(v[i].z, v[i].w)));
  }
#pragma unroll
  for (int off = 32; off >= 1; off >>= 1) mx = fmaxf(mx, __shfl_xor(mx, off));
  const int wave = tid >> 6, lane = tid & 63;
  if (lane == 0) red[wave] = mx;
  __syncthreads();
  mx = fmaxf(fmaxf(red[0], red[1]), fmaxf(red[2], red[3]));

  float s = 0.f;
#pragma unroll
  for (int i = 0; i < 8; i++) {
    v[i].x = __expf(v[i].x - mx);
    v[i].y = __expf(v[i].y - mx);
    v[i].z = __expf(v[i].z - mx);
    v[i].w = __expf(v[i].w - mx);
    s += v[i].x + v[i].y + v[i].z + v[i].w;
  }
#pragma unroll
  for (int off = 32; off >= 1; off >>= 1) s += __shfl_xor(s, off);
  if (lane == 0) red[4 + wave] = s;
  __syncthreads();
  s = red[4] + red[5] + red[6] + red[7];
  float inv = 1.0f / s;
  __bf16* pb = EMIT_BF16 ? (Wb + (size_t)blockIdx.x * M_FACTS) : nullptr;
#pragma unroll
  for (int i = 0; i < 8; i++) {
    v[i].x *= inv;
    v[i].y *= inv;
    v[i].z *= inv;
    v[i].w *= inv;
    *(float4*)(p + (size_t)(i * 256 + tid) * 4) = v[i];
    if (EMIT_BF16) {
      bf16x4_t h;
      h[0] = (__bf16)v[i].x;
      h[1] = (__bf16)v[i].y;
      h[2] = (__bf16)v[i].z;
      h[3] = (__bf16)v[i].w;
      *(bf16x4_t*)(pb + (size_t)(i * 256 + tid) * 4) = h;
    }
  }
}

// =========================================================================
// Fallback (round-1) kernels
// =========================================================================
__global__ __launch_bounds__(256) void gemm1_energy(const float* __restrict__ A,
                                                    const float* __restrict__ B,
                                                    float* __restrict__ C) {
  __shared__ __align__(16) __bf16 sAh[BM * PADK];
  __shared__ __align__(16) __bf16 sAl[BM * PADK];
  __shared__ __align__(16) __bf16 sBh[BN * PADK];
  __shared__ __align__(16) __bf16 sBl[BN * PADK];

  const int tid = threadIdx.x;
  const int row0 = blockIdx.x * BM, col0 = blockIdx.y * BN;
  const int wave = tid >> 6, lane = tid & 63;
  const int wm = wave >> 1, wn = wave & 1;
  const int lrow = lane & 15, quad = lane >> 4;

  f32x4_t acc[4][4];
#pragma unroll
  for (int i = 0; i < 4; i++)
#pragma unroll
    for (int j = 0; j < 4; j++) acc[i][j] = (f32x4_t){0.f, 0.f, 0.f, 0.f};

  for (int k0 = 0; k0 < D_DIM; k0 += BK) {
    __syncthreads();
#pragma unroll
    for (int it = 0; it < 4; it++) {
      int flat = it * 256 + tid;
      int r = flat >> 3, kq = flat & 7;
      float4 va = *(const float4*)(A + (size_t)(row0 + r) * D_DIM + k0 + kq * 4);
      float4 vb = *(const float4*)(B + (size_t)(col0 + r) * D_DIM + k0 + kq * 4);
      float fa[4] = {va.x, va.y, va.z, va.w};
      float fb[4] = {vb.x, vb.y, vb.z, vb.w};
      bf16x4_t ah, al, bh, bl;
#pragma unroll
      for (int q = 0; q < 4; q++) {
        __bf16 h = (__bf16)fa[q];
        ah[q] = h;
        al[q] = (__bf16)(fa[q] - (float)h);
        __bf16 g = (__bf16)fb[q];
        bh[q] = g;
        bl[q] = (__bf16)(fb[q] - (float)g);
      }
      *(bf16x4_t*)(sAh + r * PADK + kq * 4) = ah;
      *(bf16x4_t*)(sAl + r * PADK + kq * 4) = al;
      *(bf16x4_t*)(sBh + r * PADK + kq * 4) = bh;
      *(bf16x4_t*)(sBl + r * PADK + kq * 4) = bl;
    }
    __syncthreads();

    bf16x8_t a_h[4], a_l[4], b_h[4], b_l[4];
#pragma unroll
    for (int i = 0; i < 4; i++) {
      int ra = wm * 64 + i * 16 + lrow;
      a_h[i] = *(const bf16x8_t*)(sAh + ra * PADK + quad * 8);
      a_l[i] = *(const bf16x8_t*)(sAl + ra * PADK + quad * 8);
      int rb = wn * 64 + i * 16 + lrow;
      b_h[i] = *(const bf16x8_t*)(sBh + rb * PADK + quad * 8);
      b_l[i] = *(const bf16x8_t*)(sBl + rb * PADK + quad * 8);
    }
#pragma unroll
    for (int i = 0; i < 4; i++)
#pragma unroll
      for (int j = 0; j < 4; j++) {
        acc[i][j] = __builtin_amdgcn_mfma_f32_16x16x32_bf16(a_h[i], b_h[j], acc[i][j], 0, 0, 0);
        acc[i][j] = __builtin_amdgcn_mfma_f32_16x16x32_bf16(a_h[i], b_l[j], acc[i][j], 0, 0, 0);
        acc[i][j] = __builtin_amdgcn_mfma_f32_16x16x32_bf16(a_l[i], b_h[j], acc[i][j], 0, 0, 0);
      }
  }

#pragma unroll
  for (int i = 0; i < 4; i++) {
    int rbase = row0 + wm * 64 + i * 16 + quad * 4;
#pragma unroll
    for (int j = 0; j < 4; j++) {
      int c = col0 + wn * 64 + j * 16 + lrow;
#pragma unroll
      for (int r = 0; r < 4; r++) C[(size_t)(rbase + r) * M_FACTS + c] = acc[i][j][r];
    }
  }
}

__global__ __launch_bounds__(256) void gemm2_out(const float* __restrict__ W,
                                                 const float* __restrict__ F,
                                                 float* __restrict__ O) {
  __shared__ __align__(16) __bf16 sW[BM * PADK];
  __shared__ __align__(16) __bf16 sFt[BN * PADK];

  const int tid = threadIdx.x;
  const int row0 = blockIdx.x * BM, col0 = blockIdx.y * BN;
  const int wave = tid >> 6, lane = tid & 63;
  const int wm = wave >> 1, wn = wave & 1;
  const int lrow = lane & 15, quad = lane >> 4;

  f32x4_t acc[4][4];
#pragma unroll
  for (int i = 0; i < 4; i++)
#pragma unroll
    for (int j = 0; j < 4; j++) acc[i][j] = (f32x4_t){0.f, 0.f, 0.f, 0.f};

  for (int k0 = 0; k0 < M_FACTS; k0 += BK) {
    __syncthreads();
#pragma unroll
    for (int it = 0; it < 4; it++) {
      int flat = it * 256 + tid;
      int r = flat >> 3, kq = flat & 7;
      float4 v = *(const float4*)(W + (size_t)(row0 + r) * M_FACTS + k0 + kq * 4);
      bf16x4_t h;
      h[0] = (__bf16)v.x;
      h[1] = (__bf16)v.y;
      h[2] = (__bf16)v.z;
      h[3] = (__bf16)v.w;
      *(bf16x4_t*)(sW + r * PADK + kq * 4) = h;
    }
#pragma unroll
    for (int it = 0; it < 4; it++) {
      int flat = it * 256 + tid;
      int m = flat >> 5, dq = flat & 31;
      float4 v = *(const float4*)(F + (size_t)(k0 + m) * D_DIM + col0 + dq * 4);
      sFt[(dq * 4 + 0) * PADK + m] = (__bf16)v.x;
      sFt[(dq * 4 + 1) * PADK + m] = (__bf16)v.y;
      sFt[(dq * 4 + 2) * PADK + m] = (__bf16)v.z;
      sFt[(dq * 4 + 3) * PADK + m] = (__bf16)v.w;
    }
    __syncthreads();

    bf16x8_t a[4], b[4];
#pragma unroll
    for (int i = 0; i < 4; i++) {
      a[i] = *(const bf16x8_t*)(sW + (wm * 64 + i * 16 + lrow) * PADK + quad * 8);
      b[i] = *(const bf16x8_t*)(sFt + (wn * 64 + i * 16 + lrow) * PADK + quad * 8);
    }
#pragma unroll
    for (int i = 0; i < 4; i++)
#pragma unroll
      for (int j = 0; j < 4; j++)
        acc[i][j] = __builtin_amdgcn_mfma_f32_16x16x32_bf16(a[i], b[j], acc[i][j], 0, 0, 0);
  }

#pragma unroll
  for (int i = 0; i < 4; i++) {
    int rbase = row0 + wm * 64 + i * 16 + quad * 4;
#pragma unroll
    for (int j = 0; j < 4; j++) {
      int c = col0 + wn * 64 + j * 16 + lrow;
#pragma unroll
      for (int r = 0; r < 4; r++) O[(size_t)(rbase + r) * D_DIM + c] = acc[i][j][r];
    }
  }
}

// =========================================================================
extern "C" void kernel_launch(void* const* d_in, const int* in_sizes, int n_in,
                              void* d_out, int out_size, void* d_ws, size_t ws_size,
                              hipStream_t stream) {
  const float* E = (const float*)d_in[0];  // [N, D]
  const float* F = (const float*)d_in[1];  // [M, D]
  float* outputs = (float*)d_out;                           // [N, D]
  float* weights = (float*)d_out + (size_t)N_ROWS * D_DIM;  // [N, M]

  const size_t MB = 1ull << 20;
  char* ws = (char*)d_ws;

  // T1 layout (ws >= 144 MiB): splits @0..64 (dead after gemm1),
  //   Wb @0..128 aliases splits, Ft @128..144.
  // T2 layout (80 <= ws < 144): splits @0..64, Ft @64..80,
  //   Wb_half (64 MiB) @0 aliases splits; softmax+gemm2 run in 2 row-chunks.
  const bool t1 = ws_size >= 144 * MB;
  const bool t2 = !t1 && ws_size >= 80 * MB;
  const bool hasFtOnly = !t1 && !t2 && ws_size >= 16 * MB;

  if (t1) {
    __bf16* Eh = (__bf16*)(ws + 0 * MB);
    __bf16* El = (__bf16*)(ws + 16 * MB);
    __bf16* Fh = (__bf16*)(ws + 32 * MB);
    __bf16* Fl = (__bf16*)(ws + 48 * MB);
    __bf16* Wb = (__bf16*)(ws + 0 * MB);    // 128 MiB, aliases splits
    __bf16* Ft = (__bf16*)(ws + 128 * MB);  // 16 MiB

    transpose_f_bf16<<<dim3(M_FACTS / 64, D_DIM / 64), 256, 0, stream>>>(F, Ft);
    split_hi_lo<<<dim3((N_ROWS * D_DIM) / 1024), 256, 0, stream>>>(E, Eh, El);
    split_hi_lo<<<dim3((M_FACTS * D_DIM) / 1024), 256, 0, stream>>>(F, Fh, Fl);
    gemm1_fast<<<dim3(N_ROWS / BM, M_FACTS / BN), 256, 0, stream>>>(Eh, El, Fh, Fl, weights);
    softmax_rows_t<true><<<dim3(N_ROWS), 256, 0, stream>>>(weights, Wb);
    gemm2_fast<<<dim3(N_ROWS / BM, D_DIM / BN), 256, 0, stream>>>(Wb, Ft, outputs, 0);
  } else if (t2) {
    __bf16* Eh = (__bf16*)(ws + 0 * MB);
    __bf16* El = (__bf16*)(ws + 16 * MB);
    __bf16* Fh = (__bf16*)(ws + 32 * MB);
    __bf16* Fl = (__bf16*)(ws + 48 * MB);
    __bf16* Wb = (__bf16*)(ws + 0 * MB);   // 64 MiB half-chunk, aliases splits
    __bf16* Ft = (__bf16*)(ws + 64 * MB);  // 16 MiB

    transpose_f_bf16<<<dim3(M_FACTS / 64, D_DIM / 64), 256, 0, stream>>>(F, Ft);
    split_hi_lo<<<dim3((N_ROWS * D_DIM) / 1024), 256, 0, stream>>>(E, Eh, El);
    split_hi_lo<<<dim3((M_FACTS * D_DIM) / 1024), 256, 0, stream>>>(F, Fh, Fl);
    gemm1_fast<<<dim3(N_ROWS / BM, M_FACTS / BN), 256, 0, stream>>>(Eh, El, Fh, Fl, weights);

    const int HALF = N_ROWS / 2;
    for (int h = 0; h < 2; h++) {
      float* Wchunk = weights + (size_t)h * HALF * M_FACTS;
      softmax_rows_t<true><<<dim3(HALF), 256, 0, stream>>>(Wchunk, Wb);
      gemm2_fast<<<dim3(HALF / BM, D_DIM / BN), 256, 0, stream>>>(Wb, Ft, outputs, h * HALF);
    }
  } else {
    __bf16* Ft = (__bf16*)ws;  // 16 MiB
    if (hasFtOnly) {
      transpose_f_bf16<<<dim3(M_FACTS / 64, D_DIM / 64), 256, 0, stream>>>(F, Ft);
    }
    gemm1_energy<<<dim3(N_ROWS / BM, M_FACTS / BN), 256, 0, stream>>>(E, F, weights);
    softmax_rows_t<false><<<dim3(N_ROWS), 256, 0, stream>>>(weights, nullptr);
    if (hasFtOnly) {
      gemm2_mid<<<dim3(N_ROWS / BM, D_DIM / BN), 256, 0, stream>>>(weights, Ft, outputs);
    } else {
      gemm2_out<<<dim3(N_ROWS / BM, D_DIM / BN), 256, 0, stream>>>(weights, F, outputs);
    }
  }
}

// Round 4
// 998.841 us; speedup vs baseline: 1.5378x; 1.0127x over previous
//
#include <hip/hip_runtime.h>
#include <hip/hip_bf16.h>
#include <math.h>
#include <stdint.h>

#define N_ROWS 8192
#define M_FACTS 8192
#define D_DIM 1024

typedef __bf16 bf16x8_t __attribute__((ext_vector_type(8)));
typedef __bf16 bf16x4_t __attribute__((ext_vector_type(4)));
typedef float f32x4_t __attribute__((ext_vector_type(4)));

#define BM 128
#define BN 128
#define BK 32
#define PADK 40  // legacy padded stride for fallback kernels

// Async global->LDS, 16B per lane. LDS dest = wave-uniform base + lane*16.
__device__ __forceinline__ void gload_lds16(const void* g, void* lds) {
  __builtin_amdgcn_global_load_lds(
      (__attribute__((address_space(1))) void*)(uintptr_t)g,
      (__attribute__((address_space(3))) void*)(uint32_t)(uintptr_t)lds,
      16, 0, 0);
}

// s_waitcnt with vmcnt(N) only (expcnt/lgkmcnt unmasked). gfx9 encoding:
// [3:0] vmcnt lo, [6:4] expcnt, [11:8] lgkmcnt, [15:14] vmcnt hi.
#define WAIT_VMCNT(n) __builtin_amdgcn_s_waitcnt(0x0F70 | (n))

// =========================================================================
// Precompute kernels
// =========================================================================

__global__ __launch_bounds__(256) void split_hi_lo(const float* __restrict__ X,
                                                   __bf16* __restrict__ H,
                                                   __bf16* __restrict__ L) {
  int i = blockIdx.x * 256 + threadIdx.x;
  float4 v = ((const float4*)X)[i];
  float f[4] = {v.x, v.y, v.z, v.w};
  bf16x4_t h, l;
#pragma unroll
  for (int q = 0; q < 4; q++) {
    __bf16 hh = (__bf16)f[q];
    h[q] = hh;
    l[q] = (__bf16)(f[q] - (float)hh);
  }
  ((bf16x4_t*)H)[i] = h;
  ((bf16x4_t*)L)[i] = l;
}

// F fp32 [M][D] -> Ft bf16 [D][M]. 64x64 tiles via LDS.
__global__ __launch_bounds__(256) void transpose_f_bf16(const float* __restrict__ F,
                                                        __bf16* __restrict__ Ft) {
  __shared__ __bf16 t[64 * 68];
  const int tid = threadIdx.x;
  const int m0 = blockIdx.x * 64, d0 = blockIdx.y * 64;
#pragma unroll
  for (int p = 0; p < 4; p++) {
    int flat = p * 256 + tid;
    int m = flat >> 4, dq = flat & 15;
    float4 v = *(const float4*)(F + (size_t)(m0 + m) * D_DIM + d0 + dq * 4);
    bf16x4_t h;
    h[0] = (__bf16)v.x;
    h[1] = (__bf16)v.y;
    h[2] = (__bf16)v.z;
    h[3] = (__bf16)v.w;
    *(bf16x4_t*)(t + m * 68 + dq * 4) = h;
  }
  __syncthreads();
  int d = tid & 63, mc = (tid >> 6) * 16;
  bf16x8_t o0, o1;
#pragma unroll
  for (int j = 0; j < 8; j++) o0[j] = t[(mc + j) * 68 + d];
#pragma unroll
  for (int j = 0; j < 8; j++) o1[j] = t[(mc + 8 + j) * 68 + d];
  __bf16* dst = Ft + (size_t)(d0 + d) * M_FACTS + m0 + mc;
  *(bf16x8_t*)(dst) = o0;
  *(bf16x8_t*)(dst + 8) = o1;
}

// =========================================================================
// GEMM1 fast: energy = Eh*Fh^T + Eh*Fl^T + El*Fh^T, m97-style async staging
// =========================================================================
__global__ __launch_bounds__(256) void gemm1_fast(const __bf16* __restrict__ Eh,
                                                  const __bf16* __restrict__ El,
                                                  const __bf16* __restrict__ Fh,
                                                  const __bf16* __restrict__ Fl,
                                                  float* __restrict__ C) {
  __shared__ __bf16 sAh[BM * BK], sAl[BM * BK], sBh[BN * BK], sBl[BN * BK];
  const int tid = threadIdx.x;
  const int wave = tid >> 6, lane = tid & 63;
  const int row0 = blockIdx.x * BM, col0 = blockIdx.y * BN;
  const int wm = wave >> 1, wn = wave & 1;
  const int lrow = lane & 15, quad = lane >> 4;

  f32x4_t acc[4][4];
#pragma unroll
  for (int i = 0; i < 4; i++)
#pragma unroll
    for (int j = 0; j < 4; j++) acc[i][j] = (f32x4_t){0.f, 0.f, 0.f, 0.f};

  for (int k0 = 0; k0 < D_DIM; k0 += BK) {
#pragma unroll
    for (int r = 0; r < 2; r++) {
      int c = (r * 4 + wave) * 64 + lane;  // 16B chunk id, 0..511
      int row = c >> 2;
      int ko = (c & 3) << 3;
      size_t ga = (size_t)(row0 + row) * D_DIM + k0 + ko;
      size_t gb = (size_t)(col0 + row) * D_DIM + k0 + ko;
      gload_lds16(Eh + ga, sAh + c * 8);
      gload_lds16(El + ga, sAl + c * 8);
      gload_lds16(Fh + gb, sBh + c * 8);
      gload_lds16(Fl + gb, sBl + c * 8);
    }
    __syncthreads();

    bf16x8_t ah[4], al[4], bh[4], bl[4];
#pragma unroll
    for (int i = 0; i < 4; i++) {
      int ra = (wm * 64 + i * 16 + lrow) * BK + quad * 8;
      ah[i] = *(const bf16x8_t*)(sAh + ra);
      al[i] = *(const bf16x8_t*)(sAl + ra);
      int rb = (wn * 64 + i * 16 + lrow) * BK + quad * 8;
      bh[i] = *(const bf16x8_t*)(sBh + rb);
      bl[i] = *(const bf16x8_t*)(sBl + rb);
    }
#pragma unroll
    for (int i = 0; i < 4; i++)
#pragma unroll
      for (int j = 0; j < 4; j++) {
        acc[i][j] = __builtin_amdgcn_mfma_f32_16x16x32_bf16(ah[i], bh[j], acc[i][j], 0, 0, 0);
        acc[i][j] = __builtin_amdgcn_mfma_f32_16x16x32_bf16(ah[i], bl[j], acc[i][j], 0, 0, 0);
        acc[i][j] = __builtin_amdgcn_mfma_f32_16x16x32_bf16(al[i], bh[j], acc[i][j], 0, 0, 0);
      }
    __syncthreads();
  }

#pragma unroll
  for (int i = 0; i < 4; i++) {
    int rbase = row0 + wm * 64 + i * 16 + quad * 4;
#pragma unroll
    for (int j = 0; j < 4; j++) {
      int c = col0 + wn * 64 + j * 16 + lrow;
#pragma unroll
      for (int r = 0; r < 4; r++) C[(size_t)(rbase + r) * M_FACTS + c] = acc[i][j][r];
    }
  }
}

// =========================================================================
// GEMM2 double-buffered: O[out_row0+n][d] = sum_m Wb[n][m] * Ft[d][m].
// BK=64, 2-stage LDS pipeline with raw s_barrier + manual vmcnt waits so the
// prefetch of tile k+1 stays in flight across the barrier (critical at
// 1 wg/CU where no other block hides latency).
// =========================================================================
#define G2BK 64
__global__ __launch_bounds__(256) void gemm2_db(const __bf16* __restrict__ Wb,
                                                const __bf16* __restrict__ Ft,
                                                float* __restrict__ O,
                                                int out_row0) {
  // 2 buffers x (128x64 W + 128x64 F) bf16 = 2 x 32 KB = 64 KB LDS
  __shared__ __bf16 sW[2][BM * G2BK];
  __shared__ __bf16 sF[2][BN * G2BK];
  const int tid = threadIdx.x;
  const int wave = tid >> 6, lane = tid & 63;
  const int col0 = blockIdx.x * BN;  // d tile (col-fast for L3 reuse of Wb)
  const int row0 = blockIdx.y * BM;  // n tile
  const int wm = wave >> 1, wn = wave & 1;
  const int lrow = lane & 15, quad = lane >> 4;

  // Staging: 16 KB per array = 16 chunks of 1 KB (8 rows x 64 cols bf16).
  // Wave w stages chunks w*4..w*4+3 of each array: 8 glds / thread / stage.
  const int lr = lane >> 3;        // 0..7 row within chunk
  const int lk = (lane & 7) * 8;   // col offset, 8 bf16 = 16 B

  f32x4_t acc[4][4];
#pragma unroll
  for (int i = 0; i < 4; i++)
#pragma unroll
    for (int j = 0; j < 4; j++) acc[i][j] = (f32x4_t){0.f, 0.f, 0.f, 0.f};

  // ---- stage k-tile 0 into buffer 0
#pragma unroll
  for (int r = 0; r < 4; r++) {
    int c = wave * 4 + r;  // chunk 0..15
    int row = c * 8 + lr;
    gload_lds16(Wb + (size_t)(row0 + row) * M_FACTS + 0 + lk, &sW[0][c * 512 + lane * 8]);
    gload_lds16(Ft + (size_t)(col0 + row) * M_FACTS + 0 + lk, &sF[0][c * 512 + lane * 8]);
  }

  int buf = 0;
  for (int k0 = 0; k0 < M_FACTS; k0 += G2BK) {
    const bool more = (k0 + G2BK) < M_FACTS;
    if (more) {
      int nb = buf ^ 1;
#pragma unroll
      for (int r = 0; r < 4; r++) {
        int c = wave * 4 + r;
        int row = c * 8 + lr;
        gload_lds16(Wb + (size_t)(row0 + row) * M_FACTS + (k0 + G2BK) + lk,
                    &sW[nb][c * 512 + lane * 8]);
        gload_lds16(Ft + (size_t)(col0 + row) * M_FACTS + (k0 + G2BK) + lk,
                    &sF[nb][c * 512 + lane * 8]);
      }
      WAIT_VMCNT(8);  // oldest 8 (current buffer) landed; prefetch stays in flight
    } else {
      WAIT_VMCNT(0);
    }
    __builtin_amdgcn_s_barrier();

#pragma unroll
    for (int ks = 0; ks < G2BK; ks += 32) {
      bf16x8_t a[4], b[4];
#pragma unroll
      for (int i = 0; i < 4; i++) {
        a[i] = *(const bf16x8_t*)(&sW[buf][(wm * 64 + i * 16 + lrow) * G2BK + ks + quad * 8]);
        b[i] = *(const bf16x8_t*)(&sF[buf][(wn * 64 + i * 16 + lrow) * G2BK + ks + quad * 8]);
      }
#pragma unroll
      for (int i = 0; i < 4; i++)
#pragma unroll
        for (int j = 0; j < 4; j++)
          acc[i][j] = __builtin_amdgcn_mfma_f32_16x16x32_bf16(a[i], b[j], acc[i][j], 0, 0, 0);
    }
    __builtin_amdgcn_s_barrier();  // all waves done reading buf before it is restaged
    buf ^= 1;
  }

#pragma unroll
  for (int i = 0; i < 4; i++) {
    int rbase = out_row0 + row0 + wm * 64 + i * 16 + quad * 4;
#pragma unroll
    for (int j = 0; j < 4; j++) {
      int c = col0 + wn * 64 + j * 16 + lrow;
#pragma unroll
      for (int r = 0; r < 4; r++) O[(size_t)(rbase + r) * D_DIM + c] = acc[i][j][r];
    }
  }
}

// GEMM2 mid fallback: A = W fp32 (convert in staging), B = Ft via async.
__global__ __launch_bounds__(256) void gemm2_mid(const float* __restrict__ W,
                                                 const __bf16* __restrict__ Ft,
                                                 float* __restrict__ O) {
  __shared__ __bf16 sW[BM * BK], sF[BN * BK];
  const int tid = threadIdx.x;
  const int wave = tid >> 6, lane = tid & 63;
  const int row0 = blockIdx.x * BM, col0 = blockIdx.y * BN;
  const int wm = wave >> 1, wn = wave & 1;
  const int lrow = lane & 15, quad = lane >> 4;

  f32x4_t acc[4][4];
#pragma unroll
  for (int i = 0; i < 4; i++)
#pragma unroll
    for (int j = 0; j < 4; j++) acc[i][j] = (f32x4_t){0.f, 0.f, 0.f, 0.f};

  for (int k0 = 0; k0 < M_FACTS; k0 += BK) {
#pragma unroll
    for (int r = 0; r < 2; r++) {
      int c = (r * 4 + wave) * 64 + lane;
      int row = c >> 2;
      int ko = (c & 3) << 3;
      gload_lds16(Ft + (size_t)(col0 + row) * M_FACTS + k0 + ko, sF + c * 8);
    }
#pragma unroll
    for (int it = 0; it < 4; it++) {
      int flat = it * 256 + tid;
      int r = flat >> 3, q = flat & 7;
      float4 v = *(const float4*)(W + (size_t)(row0 + r) * M_FACTS + k0 + q * 4);
      bf16x4_t h;
      h[0] = (__bf16)v.x;
      h[1] = (__bf16)v.y;
      h[2] = (__bf16)v.z;
      h[3] = (__bf16)v.w;
      *(bf16x4_t*)(sW + r * BK + q * 4) = h;
    }
    __syncthreads();

    bf16x8_t a[4], b[4];
#pragma unroll
    for (int i = 0; i < 4; i++) {
      a[i] = *(const bf16x8_t*)(sW + (wm * 64 + i * 16 + lrow) * BK + quad * 8);
      b[i] = *(const bf16x8_t*)(sF + (wn * 64 + i * 16 + lrow) * BK + quad * 8);
    }
#pragma unroll
    for (int i = 0; i < 4; i++)
#pragma unroll
      for (int j = 0; j < 4; j++)
        acc[i][j] = __builtin_amdgcn_mfma_f32_16x16x32_bf16(a[i], b[j], acc[i][j], 0, 0, 0);
    __syncthreads();
  }

#pragma unroll
  for (int i = 0; i < 4; i++) {
    int rbase = row0 + wm * 64 + i * 16 + quad * 4;
#pragma unroll
    for (int j = 0; j < 4; j++) {
      int c = col0 + wn * 64 + j * 16 + lrow;
#pragma unroll
      for (int r = 0; r < 4; r++) O[(size_t)(rbase + r) * D_DIM + c] = acc[i][j][r];
    }
  }
}

// =========================================================================
// Softmax (optionally emitting bf16 copy of weights)
// =========================================================================
template <bool EMIT_BF16>
__global__ __launch_bounds__(256) void softmax_rows_t(float* __restrict__ W,
                                                      __bf16* __restrict__ Wb) {
  __shared__ float red[8];
  const int tid = threadIdx.x;
  float* p = W + (size_t)blockIdx.x * M_FACTS;

  float4 v[8];
  float mx = -3.4e38f;
#pragma unroll
  for (int i = 0; i < 8; i++) {
    v[i] = *(const float4*)(p + (size_t)(i * 256 + tid) * 4);
    mx = fmaxf(mx, fmaxf(fmaxf(v[i].x, v[i].y), fmaxf(v[i].z, v[i].w)));
  }
#pragma unroll
  for (int off = 32; off >= 1; off >>= 1) mx = fmaxf(mx, __shfl_xor(mx, off));
  const int wave = tid >> 6, lane = tid & 63;
  if (lane == 0) red[wave] = mx;
  __syncthreads();
  mx = fmaxf(fmaxf(red[0], red[1]), fmaxf(red[2], red[3]));

  float s = 0.f;
#pragma unroll
  for (int i = 0; i < 8; i++) {
    v[i].x = __expf(v[i].x - mx);
    v[i].y = __expf(v[i].y - mx);
    v[i].z = __expf(v[i].z - mx);
    v[i].w = __expf(v[i].w - mx);
    s += v[i].x + v[i].y + v[i].z + v[i].w;
  }
#pragma unroll
  for (int off = 32; off >= 1; off >>= 1) s += __shfl_xor(s, off);
  if (lane == 0) red[4 + wave] = s;
  __syncthreads();
  s = red[4] + red[5] + red[6] + red[7];
  float inv = 1.0f / s;
  __bf16* pb = EMIT_BF16 ? (Wb + (size_t)blockIdx.x * M_FACTS) : nullptr;
#pragma unroll
  for (int i = 0; i < 8; i++) {
    v[i].x *= inv;
    v[i].y *= inv;
    v[i].z *= inv;
    v[i].w *= inv;
    *(float4*)(p + (size_t)(i * 256 + tid) * 4) = v[i];
    if (EMIT_BF16) {
      bf16x4_t h;
      h[0] = (__bf16)v[i].x;
      h[1] = (__bf16)v[i].y;
      h[2] = (__bf16)v[i].z;
      h[3] = (__bf16)v[i].w;
      *(bf16x4_t*)(pb + (size_t)(i * 256 + tid) * 4) = h;
    }
  }
}

// =========================================================================
// Lowest-tier fallback kernels (ws < 80 MiB)
// =========================================================================
__global__ __launch_bounds__(256) void gemm1_energy(const float* __restrict__ A,
                                                    const float* __restrict__ B,
                                                    float* __restrict__ C) {
  __shared__ __align__(16) __bf16 sAh[BM * PADK];
  __shared__ __align__(16) __bf16 sAl[BM * PADK];
  __shared__ __align__(16) __bf16 sBh[BN * PADK];
  __shared__ __align__(16) __bf16 sBl[BN * PADK];

  const int tid = threadIdx.x;
  const int row0 = blockIdx.x * BM, col0 = blockIdx.y * BN;
  const int wave = tid >> 6, lane = tid & 63;
  const int wm = wave >> 1, wn = wave & 1;
  const int lrow = lane & 15, quad = lane >> 4;

  f32x4_t acc[4][4];
#pragma unroll
  for (int i = 0; i < 4; i++)
#pragma unroll
    for (int j = 0; j < 4; j++) acc[i][j] = (f32x4_t){0.f, 0.f, 0.f, 0.f};

  for (int k0 = 0; k0 < D_DIM; k0 += BK) {
    __syncthreads();
#pragma unroll
    for (int it = 0; it < 4; it++) {
      int flat = it * 256 + tid;
      int r = flat >> 3, kq = flat & 7;
      float4 va = *(const float4*)(A + (size_t)(row0 + r) * D_DIM + k0 + kq * 4);
      float4 vb = *(const float4*)(B + (size_t)(col0 + r) * D_DIM + k0 + kq * 4);
      float fa[4] = {va.x, va.y, va.z, va.w};
      float fb[4] = {vb.x, vb.y, vb.z, vb.w};
      bf16x4_t ah, al, bh, bl;
#pragma unroll
      for (int q = 0; q < 4; q++) {
        __bf16 h = (__bf16)fa[q];
        ah[q] = h;
        al[q] = (__bf16)(fa[q] - (float)h);
        __bf16 g = (__bf16)fb[q];
        bh[q] = g;
        bl[q] = (__bf16)(fb[q] - (float)g);
      }
      *(bf16x4_t*)(sAh + r * PADK + kq * 4) = ah;
      *(bf16x4_t*)(sAl + r * PADK + kq * 4) = al;
      *(bf16x4_t*)(sBh + r * PADK + kq * 4) = bh;
      *(bf16x4_t*)(sBl + r * PADK + kq * 4) = bl;
    }
    __syncthreads();

    bf16x8_t a_h[4], a_l[4], b_h[4], b_l[4];
#pragma unroll
    for (int i = 0; i < 4; i++) {
      int ra = wm * 64 + i * 16 + lrow;
      a_h[i] = *(const bf16x8_t*)(sAh + ra * PADK + quad * 8);
      a_l[i] = *(const bf16x8_t*)(sAl + ra * PADK + quad * 8);
      int rb = wn * 64 + i * 16 + lrow;
      b_h[i] = *(const bf16x8_t*)(sBh + rb * PADK + quad * 8);
      b_l[i] = *(const bf16x8_t*)(sBl + rb * PADK + quad * 8);
    }
#pragma unroll
    for (int i = 0; i < 4; i++)
#pragma unroll
      for (int j = 0; j < 4; j++) {
        acc[i][j] = __builtin_amdgcn_mfma_f32_16x16x32_bf16(a_h[i], b_h[j], acc[i][j], 0, 0, 0);
        acc[i][j] = __builtin_amdgcn_mfma_f32_16x16x32_bf16(a_h[i], b_l[j], acc[i][j], 0, 0, 0);
        acc[i][j] = __builtin_amdgcn_mfma_f32_16x16x32_bf16(a_l[i], b_h[j], acc[i][j], 0, 0, 0);
      }
  }

#pragma unroll
  for (int i = 0; i < 4; i++) {
    int rbase = row0 + wm * 64 + i * 16 + quad * 4;
#pragma unroll
    for (int j = 0; j < 4; j++) {
      int c = col0 + wn * 64 + j * 16 + lrow;
#pragma unroll
      for (int r = 0; r < 4; r++) C[(size_t)(rbase + r) * M_FACTS + c] = acc[i][j][r];
    }
  }
}

__global__ __launch_bounds__(256) void gemm2_out(const float* __restrict__ W,
                                                 const float* __restrict__ F,
                                                 float* __restrict__ O) {
  __shared__ __align__(16) __bf16 sW[BM * PADK];
  __shared__ __align__(16) __bf16 sFt[BN * PADK];

  const int tid = threadIdx.x;
  const int row0 = blockIdx.x * BM, col0 = blockIdx.y * BN;
  const int wave = tid >> 6, lane = tid & 63;
  const int wm = wave >> 1, wn = wave & 1;
  const int lrow = lane & 15, quad = lane >> 4;

  f32x4_t acc[4][4];
#pragma unroll
  for (int i = 0; i < 4; i++)
#pragma unroll
    for (int j = 0; j < 4; j++) acc[i][j] = (f32x4_t){0.f, 0.f, 0.f, 0.f};

  for (int k0 = 0; k0 < M_FACTS; k0 += BK) {
    __syncthreads();
#pragma unroll
    for (int it = 0; it < 4; it++) {
      int flat = it * 256 + tid;
      int r = flat >> 3, kq = flat & 7;
      float4 v = *(const float4*)(W + (size_t)(row0 + r) * M_FACTS + k0 + kq * 4);
      bf16x4_t h;
      h[0] = (__bf16)v.x;
      h[1] = (__bf16)v.y;
      h[2] = (__bf16)v.z;
      h[3] = (__bf16)v.w;
      *(bf16x4_t*)(sW + r * PADK + kq * 4) = h;
    }
#pragma unroll
    for (int it = 0; it < 4; it++) {
      int flat = it * 256 + tid;
      int m = flat >> 5, dq = flat & 31;
      float4 v = *(const float4*)(F + (size_t)(k0 + m) * D_DIM + col0 + dq * 4);
      sFt[(dq * 4 + 0) * PADK + m] = (__bf16)v.x;
      sFt[(dq * 4 + 1) * PADK + m] = (__bf16)v.y;
      sFt[(dq * 4 + 2) * PADK + m] = (__bf16)v.z;
      sFt[(dq * 4 + 3) * PADK + m] = (__bf16)v.w;
    }
    __syncthreads();

    bf16x8_t a[4], b[4];
#pragma unroll
    for (int i = 0; i < 4; i++) {
      a[i] = *(const bf16x8_t*)(sW + (wm * 64 + i * 16 + lrow) * PADK + quad * 8);
      b[i] = *(const bf16x8_t*)(sFt + (wn * 64 + i * 16 + lrow) * PADK + quad * 8);
    }
#pragma unroll
    for (int i = 0; i < 4; i++)
#pragma unroll
      for (int j = 0; j < 4; j++)
        acc[i][j] = __builtin_amdgcn_mfma_f32_16x16x32_bf16(a[i], b[j], acc[i][j], 0, 0, 0);
  }

#pragma unroll
  for (int i = 0; i < 4; i++) {
    int rbase = row0 + wm * 64 + i * 16 + quad * 4;
#pragma unroll
    for (int j = 0; j < 4; j++) {
      int c = col0 + wn * 64 + j * 16 + lrow;
#pragma unroll
      for (int r = 0; r < 4; r++) O[(size_t)(rbase + r) * D_DIM + c] = acc[i][j][r];
    }
  }
}

// =========================================================================
extern "C" void kernel_launch(void* const* d_in, const int* in_sizes, int n_in,
                              void* d_out, int out_size, void* d_ws, size_t ws_size,
                              hipStream_t stream) {
  const float* E = (const float*)d_in[0];  // [N, D]
  const float* F = (const float*)d_in[1];  // [M, D]
  float* outputs = (float*)d_out;                           // [N, D]
  float* weights = (float*)d_out + (size_t)N_ROWS * D_DIM;  // [N, M]

  const size_t MB = 1ull << 20;
  char* ws = (char*)d_ws;

  // Layout: Ft @ [0,16) persists; splits @ [16,80) die after gemm1;
  //   Wb @ [16,16+128) (T1, ws>=144) or Wb_half @ [16,80) (T2, ws>=80)
  //   aliases the dead splits.
  const bool t1 = ws_size >= 144 * MB;
  const bool t2 = !t1 && ws_size >= 80 * MB;
  const bool hasFtOnly = !t1 && !t2 && ws_size >= 16 * MB;

  if (t1 || t2) {
    __bf16* Ft = (__bf16*)(ws + 0 * MB);
    __bf16* Eh = (__bf16*)(ws + 16 * MB);
    __bf16* El = (__bf16*)(ws + 32 * MB);
    __bf16* Fh = (__bf16*)(ws + 48 * MB);
    __bf16* Fl = (__bf16*)(ws + 64 * MB);
    __bf16* Wb = (__bf16*)(ws + 16 * MB);  // aliases dead splits

    transpose_f_bf16<<<dim3(M_FACTS / 64, D_DIM / 64), 256, 0, stream>>>(F, Ft);
    split_hi_lo<<<dim3((N_ROWS * D_DIM) / 1024), 256, 0, stream>>>(E, Eh, El);
    split_hi_lo<<<dim3((M_FACTS * D_DIM) / 1024), 256, 0, stream>>>(F, Fh, Fl);
    gemm1_fast<<<dim3(N_ROWS / BM, M_FACTS / BN), 256, 0, stream>>>(Eh, El, Fh, Fl, weights);

    if (t1) {
      softmax_rows_t<true><<<dim3(N_ROWS), 256, 0, stream>>>(weights, Wb);
      gemm2_db<<<dim3(D_DIM / BN, N_ROWS / BM), 256, 0, stream>>>(Wb, Ft, outputs, 0);
    } else {
      const int HALF = N_ROWS / 2;
      for (int h = 0; h < 2; h++) {
        float* Wchunk = weights + (size_t)h * HALF * M_FACTS;
        softmax_rows_t<true><<<dim3(HALF), 256, 0, stream>>>(Wchunk, Wb);
        gemm2_db<<<dim3(D_DIM / BN, HALF / BM), 256, 0, stream>>>(Wb, Ft, outputs, h * HALF);
      }
    }
  } else {
    __bf16* Ft = (__bf16*)ws;  // 16 MiB
    if (hasFtOnly) {
      transpose_f_bf16<<<dim3(M_FACTS / 64, D_DIM / 64), 256, 0, stream>>>(F, Ft);
    }
    gemm1_energy<<<dim3(N_ROWS / BM, M_FACTS / BN), 256, 0, stream>>>(E, F, weights);
    softmax_rows_t<false><<<dim3(N_ROWS), 256, 0, stream>>>(weights, nullptr);
    if (hasFtOnly) {
      gemm2_mid<<<dim3(N_ROWS / BM, D_DIM / BN), 256, 0, stream>>>(weights, Ft, outputs);
    } else {
      gemm2_out<<<dim3(N_ROWS / BM, D_DIM / BN), 256, 0, stream>>>(weights, F, outputs);
    }
  }
}